// Round 5
// baseline (345.092 us; speedup 1.0000x reference)
//
#include <hip/hip_runtime.h>

using u16 = unsigned short;
using u32 = unsigned int;
typedef __attribute__((ext_vector_type(8))) short bf16x8;
typedef __attribute__((ext_vector_type(4))) float f32x4;
typedef __attribute__((ext_vector_type(4))) float float4v;
typedef __attribute__((ext_vector_type(4))) unsigned short us4;
typedef __attribute__((ext_vector_type(2))) unsigned int u32x2;

__device__ __forceinline__ u16 f2bf(float f) {
  union { float f; unsigned u; } v; v.f = f;
  unsigned r = v.u + 0x7fffu + ((v.u >> 16) & 1u);
  return (u16)(r >> 16);
}

__device__ __forceinline__ u32 cvtpk(float a, float b) {
  u32 r;
  asm("v_cvt_pk_bf16_f32 %0, %1, %2" : "=v"(r) : "v"(a), "v"(b));
  return r;
}

__device__ __forceinline__ void glds16(const void* g, void* l) {
  __builtin_amdgcn_global_load_lds(
      (const __attribute__((address_space(1))) void*)g,
      (__attribute__((address_space(3))) void*)l, 16, 0, 0);
}

__device__ __forceinline__ void lgkm0() {
  asm volatile("s_waitcnt lgkmcnt(0)" ::: "memory");
}

// counted-vmcnt barrier boundary: tile-t loads complete, deeper prefetch stays in flight
#define PIPE_BAR(N)                                        \
  __builtin_amdgcn_sched_barrier(0);                       \
  asm volatile("s_waitcnt vmcnt(" #N ")" ::: "memory");    \
  __builtin_amdgcn_s_barrier();                            \
  __builtin_amdgcn_sched_barrier(0);

#define MFMA(a, b, c) __builtin_amdgcn_mfma_f32_16x16x32_bf16((a), (b), (c), 0, 0, 0)

// scale folded into Q at projection time: 1/sqrt(64) * log2(e)
#define QSCALE 0.1803368801111601f

// ---------------- fused fp32 -> bf16 cast for all 5 inputs ----------------
__global__ __launch_bounds__(256) void cvt_all(
    const float* __restrict__ x, const float* __restrict__ wq,
    const float* __restrict__ wk, const float* __restrict__ wv,
    const float* __restrict__ wo, u16* __restrict__ x_bf,
    u16* __restrict__ wqkv, u16* __restrict__ wo_bf) {
  int i = blockIdx.x * 256 + threadIdx.x;   // 4718592 total
  const float4v* src;
  us4* dst;
  if (i < 2097152) {
    src = (const float4v*)x + i; dst = (us4*)x_bf + i;
  } else if (i < 3145728) {
    int j = i - 2097152; src = (const float4v*)wq + j; dst = (us4*)wqkv + j;
  } else if (i < 3407872) {
    int j = i - 3145728; src = (const float4v*)wk + j; dst = (us4*)wqkv + 1048576 + j;
  } else if (i < 3670016) {
    int j = i - 3407872; src = (const float4v*)wv + j; dst = (us4*)wqkv + 1310720 + j;
  } else {
    int j = i - 3670016; src = (const float4v*)wo + j; dst = (us4*)wo_bf + j;
  }
  float4v v = *src;
  us4 o;
  o[0] = f2bf(v[0]); o[1] = f2bf(v[1]); o[2] = f2bf(v[2]); o[3] = f2bf(v[3]);
  *dst = o;
}

// ---------------- RoPE cos/sin table: (L=2048, 32) float2 ----------------
__global__ __launch_bounds__(256) void rope_cs(float2* __restrict__ cs) {
  int i = blockIdx.x * 256 + threadIdx.x;
  if (i >= 2048 * 32) return;
  int t = i >> 5, fi = i & 31;
  float inv = powf(10000.f, -(float)fi / 32.f);
  float ang = (float)t * inv;
  cs[i] = make_float2(cosf(ang), sinf(ang));
}

// ---------------- plain bf16 GEMM, C = A(MxK) * B(NxK)^T, fp32 out --------
// 3-buffer LDS ring, counted vmcnt(4), one raw barrier per K-step.
__global__ __launch_bounds__(256) void gemm_bt(const u16* __restrict__ A,
                                               const u16* __restrict__ B,
                                               float* __restrict__ C,
                                               int M, int N, int K) {
  __shared__ u16 As[3][128 * 32];
  __shared__ u16 Bs[3][128 * 32];
  const int nwg = gridDim.x;
  const int cpx = nwg >> 3;
  const int flat = blockIdx.x;
  const int swb = (flat & 7) * cpx + (flat >> 3);
  const int MT = M >> 7;
  const int bx = swb % MT, by = swb / MT;

  const int tid = threadIdx.x;
  const int w = tid >> 6, l = tid & 63;
  const int wr = w >> 1, wc = w & 1;
  const int lrow = l & 15, lk = (l >> 4) * 8, jr = (l >> 4) * 4;

  f32x4 acc[4][4];
#pragma unroll
  for (int m = 0; m < 4; ++m)
#pragma unroll
    for (int n = 0; n < 4; ++n) acc[m][n] = f32x4{0.f, 0.f, 0.f, 0.f};

  const int st_row = tid >> 2;
  const int st_k = (tid & 3) * 8;
  const u16* a0 = A + (size_t)(bx * 128 + st_row) * K + st_k;
  const u16* a1 = a0 + (size_t)64 * K;
  const u16* b0 = B + (size_t)(by * 128 + st_row) * K + st_k;
  const u16* b1 = b0 + (size_t)64 * K;

  auto stage = [&](int t, int sb) {
    const size_t ko = (size_t)t * 32;
    glds16(a0 + ko, &As[sb][w * 512]);
    glds16(a1 + ko, &As[sb][2048 + w * 512]);
    glds16(b0 + ko, &Bs[sb][w * 512]);
    glds16(b1 + ko, &Bs[sb][2048 + w * 512]);
  };
  auto compute = [&](int cb) {
    bf16x8 af[4], bfr[4];
#pragma unroll
    for (int m = 0; m < 4; ++m)
      af[m] = *(const bf16x8*)&As[cb][(wr * 64 + m * 16 + lrow) * 32 + lk];
#pragma unroll
    for (int n = 0; n < 4; ++n)
      bfr[n] = *(const bf16x8*)&Bs[cb][(wc * 64 + n * 16 + lrow) * 32 + lk];
#pragma unroll
    for (int m = 0; m < 4; ++m)
#pragma unroll
      for (int n = 0; n < 4; ++n)
        acc[m][n] = MFMA(af[m], bfr[n], acc[m][n]);
  };

  const int NT = K >> 5;        // >= 3 required (K=2048 -> 64)
  stage(0, 0);
  stage(1, 1);
  int cb = 0, sb = 2;
  for (int t = 0; t < NT - 1; ++t) {
    PIPE_BAR(4)
    if (t + 2 < NT) stage(t + 2, sb);
    compute(cb);
    cb = (cb == 2) ? 0 : cb + 1;
    sb = (sb == 2) ? 0 : sb + 1;
  }
  PIPE_BAR(0)
  compute(cb);

  float* Cp = C + (size_t)(bx * 128 + wr * 64) * N + by * 128 + wc * 64;
#pragma unroll
  for (int m = 0; m < 4; ++m)
#pragma unroll
    for (int n = 0; n < 4; ++n)
#pragma unroll
      for (int j = 0; j < 4; ++j)
        Cp[(size_t)(m * 16 + jr + j) * N + n * 16 + lrow] = acc[m][n][j];
}

// ---------------- QKV GEMM with fused RoPE + layout epilogue --------------
__global__ __launch_bounds__(256) void gemm_qkv(const u16* __restrict__ A,
                                                const u16* __restrict__ B,
                                                const float2* __restrict__ cs,
                                                u16* __restrict__ q_r,
                                                u16* __restrict__ k_r,
                                                u16* __restrict__ v_t) {
  const int K = 2048;
  __shared__ u16 As[3][128 * 32];
  __shared__ u16 Bs[3][128 * 32];
  const int nwg = gridDim.x;          // 768
  const int cpx = nwg >> 3;
  const int flat = blockIdx.x;
  const int swb = (flat & 7) * cpx + (flat >> 3);
  const int bx = swb & 31, by = swb >> 5;

  const int tid = threadIdx.x;
  const int w = tid >> 6, l = tid & 63;
  const int wr = w >> 1, wc = w & 1;
  const int lrow = l & 15, lk = (l >> 4) * 8, jr = (l >> 4) * 4;

  f32x4 acc[4][4];
#pragma unroll
  for (int m = 0; m < 4; ++m)
#pragma unroll
    for (int n = 0; n < 4; ++n) acc[m][n] = f32x4{0.f, 0.f, 0.f, 0.f};

  const int st_row = tid >> 2;
  const int st_k = (tid & 3) * 8;
  const u16* a0 = A + (size_t)(bx * 128 + st_row) * K + st_k;
  const u16* a1 = a0 + (size_t)64 * K;
  const u16* b0 = B + (size_t)(by * 128 + st_row) * K + st_k;
  const u16* b1 = b0 + (size_t)64 * K;

  auto stage = [&](int t, int sbi) {
    const size_t ko = (size_t)t * 32;
    glds16(a0 + ko, &As[sbi][w * 512]);
    glds16(a1 + ko, &As[sbi][2048 + w * 512]);
    glds16(b0 + ko, &Bs[sbi][w * 512]);
    glds16(b1 + ko, &Bs[sbi][2048 + w * 512]);
  };
  auto compute = [&](int cbi) {
    bf16x8 af[4], bfr[4];
#pragma unroll
    for (int m = 0; m < 4; ++m)
      af[m] = *(const bf16x8*)&As[cbi][(wr * 64 + m * 16 + lrow) * 32 + lk];
#pragma unroll
    for (int n = 0; n < 4; ++n)
      bfr[n] = *(const bf16x8*)&Bs[cbi][(wc * 64 + n * 16 + lrow) * 32 + lk];
#pragma unroll
    for (int m = 0; m < 4; ++m)
#pragma unroll
      for (int n = 0; n < 4; ++n)
        acc[m][n] = MFMA(af[m], bfr[n], acc[m][n]);
  };

  const int NT = K >> 5;        // 64
  stage(0, 0);
  stage(1, 1);
  int cb = 0, sb = 2;
  for (int t = 0; t < NT - 1; ++t) {
    PIPE_BAR(4)
    if (t + 2 < NT) stage(t + 2, sb);
    compute(cb);
    cb = (cb == 2) ? 0 : cb + 1;
    sb = (sb == 2) ? 0 : sb + 1;
  }
  PIPE_BAR(0)
  compute(cb);

  const int cbcol = by * 128 + wc * 64;
  const int rowbase = bx * 128 + wr * 64;

  if (cbcol < 2560) {
    const bool isQ = (cbcol < 2048);
    const int h = (isQ ? cbcol : cbcol - 2048) >> 6;
    u16* dst = isQ ? q_r : k_r;
    const int nh = isQ ? 32 : 8;
#pragma unroll
    for (int m = 0; m < 4; ++m) {
#pragma unroll
      for (int j = 0; j < 4; ++j) {
        const int row = rowbase + m * 16 + jr + j;
        const int b = row >> 11, ll = row & 2047;
        const float2 c0 = cs[ll * 32 + lrow];
        const float2 c1 = cs[ll * 32 + 16 + lrow];
        u16* op = dst + (((size_t)b * nh + h) * 2048 + ll) * 64;
#pragma unroll
        for (int n = 0; n < 4; ++n) {
          const float val = acc[m][n][j];
          const float oth = acc[m][n ^ 2][j];
          const float cx = (n & 1) ? c1.x : c0.x;
          const float sy = (n & 1) ? c1.y : c0.y;
          float r = (n < 2) ? (val * cx - oth * sy) : (val * cx + oth * sy);
          if (isQ) r *= QSCALE;
          op[n * 16 + lrow] = f2bf(r);
        }
      }
    }
  } else {
    const int h = (cbcol - 2560) >> 6;
#pragma unroll
    for (int m = 0; m < 4; ++m) {
      const int row0 = rowbase + m * 16 + jr;
      const int b = row0 >> 11, l0 = row0 & 2047;
#pragma unroll
      for (int n = 0; n < 4; ++n) {
        const int d = n * 16 + lrow;
        us4 pk;
#pragma unroll
        for (int j = 0; j < 4; ++j) pk[j] = f2bf(acc[m][n][j]);
        *(us4*)&v_t[(((size_t)b * 8 + h) * 64 + d) * 2048 + l0] = pk;
      }
    }
  }
}

// ---------------- causal GQA flash attention v4 (unchanged) ----------------
__global__ __launch_bounds__(256) void attn4(const u16* __restrict__ q_r,
                                             const u16* __restrict__ k_r,
                                             const u16* __restrict__ v_t,
                                             u16* __restrict__ attn_o) {
  __shared__ u16 Kl[2][64 * 64];    // [buf][kv][d] swizzled
  __shared__ u16 Vl[2][64 * 64];    // [buf][d][kv] swizzled
  __shared__ u16 Pl[4][32 * 64];    // per-wave [q][kv] swizzled

  const int bid = blockIdx.x;             // 1024 blocks
  const int q0 = (63 - (bid >> 4)) * 32;  // longest blocks first
  const int bk = bid & 15;
  const int b = bk >> 3, kvh = bk & 7;

  const int tid = threadIdx.x;
  const int w = tid >> 6;                 // wave = q-head within kv group
  const int l = tid & 63;
  const int h = kvh * 4 + w;
  const int lr = l & 15, lg = l >> 4;

  const u16* Qp = q_r + (((size_t)(b * 32 + h)) * 2048 + q0) * 64;
  const u16* Kp = k_r + ((size_t)(b * 8 + kvh)) * 2048 * 64;
  const u16* Vp = v_t + ((size_t)(b * 8 + kvh)) * 64 * 2048;

  bf16x8 qf[2][2];
#pragma unroll
  for (int qh = 0; qh < 2; ++qh)
#pragma unroll
    for (int kh = 0; kh < 2; ++kh)
      qf[qh][kh] = *(const bf16x8*)&Qp[(qh * 16 + lr) * 64 + kh * 32 + lg * 8];

  bf16x8 ones;
#pragma unroll
  for (int i = 0; i < 8; ++i) ones[i] = (short)0x3F80;   // bf16 1.0

  f32x4 o[2][4];
#pragma unroll
  for (int qh = 0; qh < 2; ++qh)
#pragma unroll
    for (int nf = 0; nf < 4; ++nf) o[qh][nf] = f32x4{0.f, 0.f, 0.f, 0.f};
  f32x4 lsv[2] = {f32x4{0.f, 0.f, 0.f, 0.f}, f32x4{0.f, 0.f, 0.f, 0.f}};

  const int sr = l >> 3;
  const int sc = (l & 7) ^ sr;            // pre-swizzled source chunk
  const int nt = (q0 + 95) >> 6;
  const int nfull = q0 >> 6;

  auto stage = [&](int bufi, int t) {
#pragma unroll
    for (int p = 0; p < 2; ++p) {
      const int r = p * 32 + w * 8 + sr;
      glds16(Kp + (size_t)(t * 64 + r) * 64 + sc * 8, &Kl[bufi][(p * 32 + w * 8) * 64]);
      glds16(Vp + (size_t)r * 2048 + t * 64 + sc * 8, &Vl[bufi][(p * 32 + w * 8) * 64]);
    }
  };

  stage(0, 0);
  int buf = 0;
  for (int t = 0; t < nt; ++t) {
    __syncthreads();
    if (t + 1 < nt) stage(buf ^ 1, t + 1);
    const int kv0 = t * 64;

    // ---- QK^T (swapped: A=K rows, B=Q rows); exp2-domain scores ----
    f32x4 s[2][4];
#pragma unroll
    for (int qh = 0; qh < 2; ++qh)
#pragma unroll
      for (int kv4 = 0; kv4 < 4; ++kv4) s[qh][kv4] = f32x4{0.f, 0.f, 0.f, 0.f};
    const int swz = (lr & 7) << 4;
#pragma unroll
    for (int kv4 = 0; kv4 < 4; ++kv4) {
      const int kvr = kv4 * 16 + lr;
#pragma unroll
      for (int kh = 0; kh < 2; ++kh) {
        bf16x8 kf = *(const bf16x8*)((const char*)&Kl[buf][kvr * 64] +
                                     ((kh * 64 + lg * 16) ^ swz));
        s[0][kv4] = MFMA(kf, qf[0][kh], s[0][kv4]);
        s[1][kv4] = MFMA(kf, qf[1][kh], s[1][kv4]);
      }
    }

    const bool diag = (t >= nfull);       // one masked tile per block
#pragma unroll
    for (int qh = 0; qh < 2; ++qh) {
      const int qrow = q0 + qh * 16 + lr;
      if (diag) {
#pragma unroll
        for (int kv4 = 0; kv4 < 4; ++kv4)
#pragma unroll
          for (int j = 0; j < 4; ++j)
            if ((kv0 + kv4 * 16 + lg * 4 + j) > qrow) s[qh][kv4][j] = -1e30f;
      }
#pragma unroll
      for (int kv4 = 0; kv4 < 4; ++kv4) {
        u32x2 pk;
        pk[0] = cvtpk(exp2f(s[qh][kv4][0]), exp2f(s[qh][kv4][1]));
        pk[1] = cvtpk(exp2f(s[qh][kv4][2]), exp2f(s[qh][kv4][3]));
        *(u32x2*)((char*)&Pl[w][(qh * 16 + lr) * 64] +
                  ((kv4 * 32 + lg * 8) ^ swz)) = pk;
      }
    }

    // ---- PV: A=P, B=V^T rows; lsum via ones-fragment MFMA ----
    lgkm0();
#pragma unroll
    for (int k2 = 0; k2 < 2; ++k2) {
      bf16x8 pa[2];
#pragma unroll
      for (int qh = 0; qh < 2; ++qh)
        pa[qh] = *(const bf16x8*)((const char*)&Pl[w][(qh * 16 + lr) * 64] +
                                  ((k2 * 64 + lg * 16) ^ swz));
      lsv[0] = MFMA(pa[0], ones, lsv[0]);
      lsv[1] = MFMA(pa[1], ones, lsv[1]);
#pragma unroll
      for (int nf = 0; nf < 4; ++nf) {
        const int d = nf * 16 + lr;
        bf16x8 bv = *(const bf16x8*)((const char*)&Vl[buf][d * 64] +
                                     ((k2 * 64 + lg * 16) ^ swz));
        o[0][nf] = MFMA(pa[0], bv, o[0][nf]);
        o[1][nf] = MFMA(pa[1], bv, o[1][nf]);
      }
    }
    buf ^= 1;
  }

  // ---- epilogue: lsv already in o[] layout; divide & store ----
  u16* Op = attn_o + (size_t)b * 2048 * 2048 + h * 64;
#pragma unroll
  for (int qh = 0; qh < 2; ++qh) {
#pragma unroll
    for (int j = 0; j < 4; ++j) {
      const float inv = __builtin_amdgcn_rcpf(lsv[qh][j]);
      const int row = q0 + qh * 16 + lg * 4 + j;
#pragma unroll
      for (int nf = 0; nf < 4; ++nf)
        Op[(size_t)row * 2048 + nf * 16 + lr] = f2bf(o[qh][nf][j] * inv);
    }
  }
}

// ---------------- launch ----------------
extern "C" void kernel_launch(void* const* d_in, const int* in_sizes, int n_in,
                              void* d_out, int out_size, void* d_ws, size_t ws_size,
                              hipStream_t stream) {
  const float* x = (const float*)d_in[0];
  const float* wq = (const float*)d_in[1];
  const float* wk = (const float*)d_in[2];
  const float* wv = (const float*)d_in[3];
  const float* wo = (const float*)d_in[4];
  float* out = (float*)d_out;

  char* p = (char*)d_ws;
  auto alloc = [&](size_t bytes) {
    char* r = p;
    p += (bytes + 255) & ~(size_t)255;
    return r;
  };
  u16* x_bf    = (u16*)alloc((size_t)8388608 * 2);
  u16* wqkv    = (u16*)alloc((size_t)3072 * 2048 * 2);
  u16* wo_bf   = (u16*)alloc((size_t)2048 * 2048 * 2);
  u16* q_r     = (u16*)alloc((size_t)8388608 * 2);
  u16* k_r     = (u16*)alloc((size_t)2097152 * 2);
  u16* v_t     = (u16*)alloc((size_t)2097152 * 2);
  u16* attn_o  = (u16*)alloc((size_t)8388608 * 2);
  float2* cs   = (float2*)alloc((size_t)65536 * 8);

  cvt_all<<<18432, 256, 0, stream>>>(x, wq, wk, wv, wo, x_bf, wqkv, wo_bf);
  rope_cs<<<256, 256, 0, stream>>>(cs);

  // QKV projection with fused RoPE/layout: (4096x2048) x (3072x2048)^T
  gemm_qkv<<<768, 256, 0, stream>>>(x_bf, wqkv, cs, q_r, k_r, v_t);

  attn4<<<1024, 256, 0, stream>>>(q_r, k_r, v_t, attn_o);

  // output projection: (4096x2048) x (2048x2048)^T -> (4096x2048)
  gemm_bt<<<512, 256, 0, stream>>>(attn_o, wo_bf, out, 4096, 2048, 2048);
}

// Round 7
// 318.223 us; speedup vs baseline: 1.0844x; 1.0844x over previous
//
#include <hip/hip_runtime.h>

using u16 = unsigned short;
using u32 = unsigned int;
typedef __attribute__((ext_vector_type(8))) short bf16x8;
typedef __attribute__((ext_vector_type(4))) float f32x4;
typedef __attribute__((ext_vector_type(4))) float float4v;
typedef __attribute__((ext_vector_type(4))) unsigned short us4;
typedef __attribute__((ext_vector_type(2))) unsigned int u32x2;

__device__ __forceinline__ u16 f2bf(float f) {
  union { float f; unsigned u; } v; v.f = f;
  unsigned r = v.u + 0x7fffu + ((v.u >> 16) & 1u);
  return (u16)(r >> 16);
}

__device__ __forceinline__ u32 cvtpk(float a, float b) {
  u32 r;
  asm("v_cvt_pk_bf16_f32 %0, %1, %2" : "=v"(r) : "v"(a), "v"(b));
  return r;
}

__device__ __forceinline__ void glds16(const void* g, void* l) {
  __builtin_amdgcn_global_load_lds(
      (const __attribute__((address_space(1))) void*)g,
      (__attribute__((address_space(3))) void*)l, 16, 0, 0);
}

__device__ __forceinline__ void lgkm0() {
  asm volatile("s_waitcnt lgkmcnt(0)" ::: "memory");
}

// top-of-iter gate: this wave's staged tile landed; barrier joins all waves.
// sched_barrier pins the following ds_reads below the gate.
#define TILE_GATE()                                      \
  asm volatile("s_waitcnt vmcnt(0)" ::: "memory");       \
  __builtin_amdgcn_s_barrier();                          \
  __builtin_amdgcn_sched_barrier(0);

#define MFMA(a, b, c) __builtin_amdgcn_mfma_f32_16x16x32_bf16((a), (b), (c), 0, 0, 0)

// scale folded into Q at projection time: 1/sqrt(64) * log2(e)
#define QSCALE 0.1803368801111601f

// ---------------- fused fp32 -> bf16 cast for all 5 inputs ----------------
__global__ __launch_bounds__(256) void cvt_all(
    const float* __restrict__ x, const float* __restrict__ wq,
    const float* __restrict__ wk, const float* __restrict__ wv,
    const float* __restrict__ wo, u16* __restrict__ x_bf,
    u16* __restrict__ wqkv, u16* __restrict__ wo_bf) {
  int i = blockIdx.x * 256 + threadIdx.x;   // 4718592 total
  const float4v* src;
  us4* dst;
  if (i < 2097152) {
    src = (const float4v*)x + i; dst = (us4*)x_bf + i;
  } else if (i < 3145728) {
    int j = i - 2097152; src = (const float4v*)wq + j; dst = (us4*)wqkv + j;
  } else if (i < 3407872) {
    int j = i - 3145728; src = (const float4v*)wk + j; dst = (us4*)wqkv + 1048576 + j;
  } else if (i < 3670016) {
    int j = i - 3407872; src = (const float4v*)wv + j; dst = (us4*)wqkv + 1310720 + j;
  } else {
    int j = i - 3670016; src = (const float4v*)wo + j; dst = (us4*)wo_bf + j;
  }
  float4v v = *src;
  us4 o;
  o[0] = f2bf(v[0]); o[1] = f2bf(v[1]); o[2] = f2bf(v[2]); o[3] = f2bf(v[3]);
  *dst = o;
}

// ---------------- RoPE cos/sin table: (L=2048, 32) float2 ----------------
__global__ __launch_bounds__(256) void rope_cs(float2* __restrict__ cs) {
  int i = blockIdx.x * 256 + threadIdx.x;
  if (i >= 2048 * 32) return;
  int t = i >> 5, fi = i & 31;
  float inv = powf(10000.f, -(float)fi / 32.f);
  float ang = (float)t * inv;
  cs[i] = make_float2(cosf(ang), sinf(ang));
}

// ---------------- QKV GEMM: 256x256, BK=64, 8 waves, phase-split ----------
// A = x_bf (4096x2048), B = wqkv (3072x2048)^T, fused RoPE epilogue.
// Gate-then-stage (2-buffer), full-tile prefetch in ph0, T2 XOR swizzle.
__global__ __launch_bounds__(512, 2) void gemm_qkv(const u16* __restrict__ Ag,
                                                   const u16* __restrict__ Bg,
                                                   const float2* __restrict__ cs,
                                                   u16* __restrict__ q_r,
                                                   u16* __restrict__ k_r,
                                                   u16* __restrict__ v_t) {
  __shared__ u16 Al[2][256 * 64];   // 64KB
  __shared__ u16 Bl[2][256 * 64];   // 64KB

  const int nwg = gridDim.x;        // 192
  const int cpx = nwg >> 3;
  const int flat = blockIdx.x;
  const int swb = (flat & 7) * cpx + (flat >> 3);
  const int bx = swb & 15, by = swb >> 4;
  const int bmRow = bx * 256, bnRow = by * 256;

  const int tid = threadIdx.x;
  const int w = tid >> 6, l = tid & 63;
  const int wm = w >> 2, wn = w & 3;      // rows wm*128, cols wn*64
  const int lr = l & 15, lg = l >> 4;
  const int rb7 = lr & 7;

  // staging: each wave owns 32 rows of A-tile and 32 rows of B-tile
  const int srow = l >> 3;
  const int sch = (l & 7) ^ srow;         // pre-swizzled source chunk (T2)
  const int reg0 = w * 32;
  const u16* a_src = Ag + (size_t)(bmRow + reg0 + srow) * 2048 + sch * 8;
  const u16* b_src = Bg + (size_t)(bnRow + reg0 + srow) * 2048 + sch * 8;

  auto stageTile = [&](int kt, int bufi) {
    const int kc = kt * 64;
#pragma unroll
    for (int i = 0; i < 4; ++i)
      glds16(a_src + (size_t)i * 8 * 2048 + kc, &Al[bufi][(reg0 + i * 8) * 64]);
#pragma unroll
    for (int i = 0; i < 4; ++i)
      glds16(b_src + (size_t)i * 8 * 2048 + kc, &Bl[bufi][(reg0 + i * 8) * 64]);
  };
  // swizzled ds_read: row in [0,256), chunk g in [0,8)
  auto rd = [&](const u16* base, int row, int g) -> bf16x8 {
    return *(const bf16x8*)((const char*)base + row * 128 + (((g) ^ rb7) << 4));
  };

  f32x4 acc[8][4];
#pragma unroll
  for (int m = 0; m < 8; ++m)
#pragma unroll
    for (int n = 0; n < 4; ++n) acc[m][n] = f32x4{0.f, 0.f, 0.f, 0.f};

  bf16x8 af[4][2], bfr[4][2];
  const int NT = 32;

  stageTile(0, 0);
  for (int t = 0; t < NT; ++t) {
    const int cur = t & 1;
    const u16* Ab = &Al[cur][0];
    const u16* Bb = &Bl[cur][0];

    TILE_GATE()                           // tile t landed (all waves)
    if (t + 1 < NT) stageTile(t + 1, cur ^ 1);

    // ph0: A m0-3 + B n0-1 reads -> MFMA quad
#pragma unroll
    for (int m = 0; m < 4; ++m)
#pragma unroll
      for (int kk = 0; kk < 2; ++kk)
        af[m][kk] = rd(Ab, wm * 128 + m * 16 + lr, kk * 4 + lg);
#pragma unroll
    for (int n = 0; n < 2; ++n)
#pragma unroll
      for (int kk = 0; kk < 2; ++kk)
        bfr[n][kk] = rd(Bb, wn * 64 + n * 16 + lr, kk * 4 + lg);
    __builtin_amdgcn_s_barrier();
    __builtin_amdgcn_s_setprio(1);
#pragma unroll
    for (int m = 0; m < 4; ++m)
#pragma unroll
      for (int n = 0; n < 2; ++n)
#pragma unroll
        for (int kk = 0; kk < 2; ++kk)
          acc[m][n] = MFMA(af[m][kk], bfr[n][kk], acc[m][n]);
    __builtin_amdgcn_s_setprio(0);
    __builtin_amdgcn_s_barrier();

    // ph1: B n2-3 reads -> MFMA quad
#pragma unroll
    for (int n = 2; n < 4; ++n)
#pragma unroll
      for (int kk = 0; kk < 2; ++kk)
        bfr[n][kk] = rd(Bb, wn * 64 + n * 16 + lr, kk * 4 + lg);
    __builtin_amdgcn_s_barrier();
    __builtin_amdgcn_s_setprio(1);
#pragma unroll
    for (int m = 0; m < 4; ++m)
#pragma unroll
      for (int n = 2; n < 4; ++n)
#pragma unroll
        for (int kk = 0; kk < 2; ++kk)
          acc[m][n] = MFMA(af[m][kk], bfr[n][kk], acc[m][n]);
    __builtin_amdgcn_s_setprio(0);
    __builtin_amdgcn_s_barrier();

    // ph2: A m4-7 reads (reuse af regs; ph1 consumed old af) -> MFMA quad
#pragma unroll
    for (int m = 0; m < 4; ++m)
#pragma unroll
      for (int kk = 0; kk < 2; ++kk)
        af[m][kk] = rd(Ab, wm * 128 + 64 + m * 16 + lr, kk * 4 + lg);
    __builtin_amdgcn_s_barrier();
    __builtin_amdgcn_s_setprio(1);
#pragma unroll
    for (int m = 0; m < 4; ++m)
#pragma unroll
      for (int n = 0; n < 2; ++n)
#pragma unroll
        for (int kk = 0; kk < 2; ++kk)
          acc[4 + m][n] = MFMA(af[m][kk], bfr[n][kk], acc[4 + m][n]);
    __builtin_amdgcn_s_setprio(0);
    __builtin_amdgcn_s_barrier();

    // ph3: no reads -> MFMA quad (gate of next iter closes the tile)
    __builtin_amdgcn_s_setprio(1);
#pragma unroll
    for (int m = 0; m < 4; ++m)
#pragma unroll
      for (int n = 2; n < 4; ++n)
#pragma unroll
        for (int kk = 0; kk < 2; ++kk)
          acc[4 + m][n] = MFMA(af[m][kk], bfr[n][kk], acc[4 + m][n]);
    __builtin_amdgcn_s_setprio(0);
  }

  // ---- epilogue: fused RoPE / layout (wave col span = 64 = one head) ----
  const int cbcol = bnRow + wn * 64;
  const int rowbase = bmRow + wm * 128;

  if (cbcol < 2560) {
    const bool isQ = (cbcol < 2048);
    const int h = (isQ ? cbcol : cbcol - 2048) >> 6;
    u16* dst = isQ ? q_r : k_r;
    const int nh = isQ ? 32 : 8;
#pragma unroll
    for (int m = 0; m < 8; ++m) {
#pragma unroll
      for (int j = 0; j < 4; ++j) {
        const int row = rowbase + m * 16 + lg * 4 + j;
        const int b = row >> 11, ll = row & 2047;
        const float2 c0 = cs[ll * 32 + lr];
        const float2 c1 = cs[ll * 32 + 16 + lr];
        u16* op = dst + (((size_t)b * nh + h) * 2048 + ll) * 64;
#pragma unroll
        for (int n = 0; n < 4; ++n) {
          const float val = acc[m][n][j];
          const float oth = acc[m][n ^ 2][j];
          const float cx = (n & 1) ? c1.x : c0.x;
          const float sy = (n & 1) ? c1.y : c0.y;
          float r = (n < 2) ? (val * cx - oth * sy) : (val * cx + oth * sy);
          if (isQ) r *= QSCALE;
          op[n * 16 + lr] = f2bf(r);
        }
      }
    }
  } else {
    const int h = (cbcol - 2560) >> 6;
#pragma unroll
    for (int m = 0; m < 8; ++m) {
      const int row0 = rowbase + m * 16 + lg * 4;
      const int b = row0 >> 11, l0 = row0 & 2047;
#pragma unroll
      for (int n = 0; n < 4; ++n) {
        const int d = n * 16 + lr;
        us4 pk;
#pragma unroll
        for (int j = 0; j < 4; ++j) pk[j] = f2bf(acc[m][n][j]);
        *(us4*)&v_t[(((size_t)b * 8 + h) * 64 + d) * 2048 + l0] = pk;
      }
    }
  }
}

// ---------------- out-proj GEMM: 256x128 tile, same pipeline ----------------
// C = A(4096x2048) * B(2048x2048)^T, fp32 out. Grid 256 (full CU fill).
__global__ __launch_bounds__(512, 2) void gemm_o(const u16* __restrict__ Ag,
                                                 const u16* __restrict__ Bg,
                                                 float* __restrict__ C) {
  __shared__ u16 Al[2][256 * 64];   // 64KB
  __shared__ u16 Bl[2][128 * 64];   // 32KB

  const int nwg = gridDim.x;        // 256
  const int cpx = nwg >> 3;
  const int flat = blockIdx.x;
  const int swb = (flat & 7) * cpx + (flat >> 3);
  const int bx = swb & 15, by = swb >> 4;
  const int bmRow = bx * 256, bnRow = by * 128;

  const int tid = threadIdx.x;
  const int w = tid >> 6, l = tid & 63;
  const int wm = w >> 1, wn = w & 1;      // rows wm*64, cols wn*64
  const int lr = l & 15, lg = l >> 4;
  const int rb7 = lr & 7;

  const int srow = l >> 3;
  const int sch = (l & 7) ^ srow;
  const int areg = w * 32;                // A: 32 rows/wave
  const int breg = w * 16;                // B: 16 rows/wave
  const u16* a_src = Ag + (size_t)(bmRow + areg + srow) * 2048 + sch * 8;
  const u16* b_src = Bg + (size_t)(bnRow + breg + srow) * 2048 + sch * 8;

  auto stageTile = [&](int kt, int bufi) {
    const int kc = kt * 64;
#pragma unroll
    for (int i = 0; i < 4; ++i)
      glds16(a_src + (size_t)i * 8 * 2048 + kc, &Al[bufi][(areg + i * 8) * 64]);
#pragma unroll
    for (int i = 0; i < 2; ++i)
      glds16(b_src + (size_t)i * 8 * 2048 + kc, &Bl[bufi][(breg + i * 8) * 64]);
  };
  auto rd = [&](const u16* base, int row, int g) -> bf16x8 {
    return *(const bf16x8*)((const char*)base + row * 128 + (((g) ^ rb7) << 4));
  };

  f32x4 acc[4][4];
#pragma unroll
  for (int m = 0; m < 4; ++m)
#pragma unroll
    for (int n = 0; n < 4; ++n) acc[m][n] = f32x4{0.f, 0.f, 0.f, 0.f};

  bf16x8 af[4][2], bfr[4][2];
  const int NT = 32;

  stageTile(0, 0);
  for (int t = 0; t < NT; ++t) {
    const int cur = t & 1;
    const u16* Ab = &Al[cur][0];
    const u16* Bb = &Bl[cur][0];

    TILE_GATE()
    if (t + 1 < NT) stageTile(t + 1, cur ^ 1);

    // ph0: A m0-3 + B n0-1 -> MFMA
#pragma unroll
    for (int m = 0; m < 4; ++m)
#pragma unroll
      for (int kk = 0; kk < 2; ++kk)
        af[m][kk] = rd(Ab, wm * 64 + m * 16 + lr, kk * 4 + lg);
#pragma unroll
    for (int n = 0; n < 2; ++n)
#pragma unroll
      for (int kk = 0; kk < 2; ++kk)
        bfr[n][kk] = rd(Bb, wn * 64 + n * 16 + lr, kk * 4 + lg);
    __builtin_amdgcn_s_barrier();
    __builtin_amdgcn_s_setprio(1);
#pragma unroll
    for (int m = 0; m < 4; ++m)
#pragma unroll
      for (int n = 0; n < 2; ++n)
#pragma unroll
        for (int kk = 0; kk < 2; ++kk)
          acc[m][n] = MFMA(af[m][kk], bfr[n][kk], acc[m][n]);
    __builtin_amdgcn_s_setprio(0);
    __builtin_amdgcn_s_barrier();

    // ph1: B n2-3 -> MFMA
#pragma unroll
    for (int n = 2; n < 4; ++n)
#pragma unroll
      for (int kk = 0; kk < 2; ++kk)
        bfr[n][kk] = rd(Bb, wn * 64 + n * 16 + lr, kk * 4 + lg);
    __builtin_amdgcn_s_barrier();
    __builtin_amdgcn_s_setprio(1);
#pragma unroll
    for (int m = 0; m < 4; ++m)
#pragma unroll
      for (int n = 2; n < 4; ++n)
#pragma unroll
        for (int kk = 0; kk < 2; ++kk)
          acc[m][n] = MFMA(af[m][kk], bfr[n][kk], acc[m][n]);
    __builtin_amdgcn_s_setprio(0);
  }

  float* Cp = C + (size_t)(bmRow + wm * 64) * 2048 + bnRow + wn * 64;
#pragma unroll
  for (int m = 0; m < 4; ++m)
#pragma unroll
    for (int n = 0; n < 4; ++n)
#pragma unroll
      for (int j = 0; j < 4; ++j)
        Cp[(size_t)(m * 16 + lg * 4 + j) * 2048 + n * 16 + lr] = acc[m][n][j];
}

// ---------------- causal GQA flash attention v4 (unchanged) ----------------
__global__ __launch_bounds__(256) void attn4(const u16* __restrict__ q_r,
                                             const u16* __restrict__ k_r,
                                             const u16* __restrict__ v_t,
                                             u16* __restrict__ attn_o) {
  __shared__ u16 Kl[2][64 * 64];    // [buf][kv][d] swizzled
  __shared__ u16 Vl[2][64 * 64];    // [buf][d][kv] swizzled
  __shared__ u16 Pl[4][32 * 64];    // per-wave [q][kv] swizzled

  const int bid = blockIdx.x;             // 1024 blocks
  const int q0 = (63 - (bid >> 4)) * 32;  // longest blocks first
  const int bk = bid & 15;
  const int b = bk >> 3, kvh = bk & 7;

  const int tid = threadIdx.x;
  const int w = tid >> 6;                 // wave = q-head within kv group
  const int l = tid & 63;
  const int h = kvh * 4 + w;
  const int lr = l & 15, lg = l >> 4;

  const u16* Qp = q_r + (((size_t)(b * 32 + h)) * 2048 + q0) * 64;
  const u16* Kp = k_r + ((size_t)(b * 8 + kvh)) * 2048 * 64;
  const u16* Vp = v_t + ((size_t)(b * 8 + kvh)) * 64 * 2048;

  bf16x8 qf[2][2];
#pragma unroll
  for (int qh = 0; qh < 2; ++qh)
#pragma unroll
    for (int kh = 0; kh < 2; ++kh)
      qf[qh][kh] = *(const bf16x8*)&Qp[(qh * 16 + lr) * 64 + kh * 32 + lg * 8];

  bf16x8 ones;
#pragma unroll
  for (int i = 0; i < 8; ++i) ones[i] = (short)0x3F80;   // bf16 1.0

  f32x4 o[2][4];
#pragma unroll
  for (int qh = 0; qh < 2; ++qh)
#pragma unroll
    for (int nf = 0; nf < 4; ++nf) o[qh][nf] = f32x4{0.f, 0.f, 0.f, 0.f};
  f32x4 lsv[2] = {f32x4{0.f, 0.f, 0.f, 0.f}, f32x4{0.f, 0.f, 0.f, 0.f}};

  const int sr = l >> 3;
  const int sc = (l & 7) ^ sr;            // pre-swizzled source chunk
  const int nt = (q0 + 95) >> 6;
  const int nfull = q0 >> 6;

  auto stage = [&](int bufi, int t) {
#pragma unroll
    for (int p = 0; p < 2; ++p) {
      const int r = p * 32 + w * 8 + sr;
      glds16(Kp + (size_t)(t * 64 + r) * 64 + sc * 8, &Kl[bufi][(p * 32 + w * 8) * 64]);
      glds16(Vp + (size_t)r * 2048 + t * 64 + sc * 8, &Vl[bufi][(p * 32 + w * 8) * 64]);
    }
  };

  stage(0, 0);
  int buf = 0;
  for (int t = 0; t < nt; ++t) {
    __syncthreads();
    if (t + 1 < nt) stage(buf ^ 1, t + 1);
    const int kv0 = t * 64;

    // ---- QK^T (swapped: A=K rows, B=Q rows); exp2-domain scores ----
    f32x4 s[2][4];
#pragma unroll
    for (int qh = 0; qh < 2; ++qh)
#pragma unroll
      for (int kv4 = 0; kv4 < 4; ++kv4) s[qh][kv4] = f32x4{0.f, 0.f, 0.f, 0.f};
    const int swz = (lr & 7) << 4;
#pragma unroll
    for (int kv4 = 0; kv4 < 4; ++kv4) {
      const int kvr = kv4 * 16 + lr;
#pragma unroll
      for (int kh = 0; kh < 2; ++kh) {
        bf16x8 kf = *(const bf16x8*)((const char*)&Kl[buf][kvr * 64] +
                                     ((kh * 64 + lg * 16) ^ swz));
        s[0][kv4] = MFMA(kf, qf[0][kh], s[0][kv4]);
        s[1][kv4] = MFMA(kf, qf[1][kh], s[1][kv4]);
      }
    }

    const bool diag = (t >= nfull);       // one masked tile per block
#pragma unroll
    for (int qh = 0; qh < 2; ++qh) {
      const int qrow = q0 + qh * 16 + lr;
      if (diag) {
#pragma unroll
        for (int kv4 = 0; kv4 < 4; ++kv4)
#pragma unroll
          for (int j = 0; j < 4; ++j)
            if ((kv0 + kv4 * 16 + lg * 4 + j) > qrow) s[qh][kv4][j] = -1e30f;
      }
#pragma unroll
      for (int kv4 = 0; kv4 < 4; ++kv4) {
        u32x2 pk;
        pk[0] = cvtpk(exp2f(s[qh][kv4][0]), exp2f(s[qh][kv4][1]));
        pk[1] = cvtpk(exp2f(s[qh][kv4][2]), exp2f(s[qh][kv4][3]));
        *(u32x2*)((char*)&Pl[w][(qh * 16 + lr) * 64] +
                  ((kv4 * 32 + lg * 8) ^ swz)) = pk;
      }
    }

    // ---- PV: A=P, B=V^T rows; lsum via ones-fragment MFMA ----
    lgkm0();
#pragma unroll
    for (int k2 = 0; k2 < 2; ++k2) {
      bf16x8 pa[2];
#pragma unroll
      for (int qh = 0; qh < 2; ++qh)
        pa[qh] = *(const bf16x8*)((const char*)&Pl[w][(qh * 16 + lr) * 64] +
                                  ((k2 * 64 + lg * 16) ^ swz));
      lsv[0] = MFMA(pa[0], ones, lsv[0]);
      lsv[1] = MFMA(pa[1], ones, lsv[1]);
#pragma unroll
      for (int nf = 0; nf < 4; ++nf) {
        const int d = nf * 16 + lr;
        bf16x8 bv = *(const bf16x8*)((const char*)&Vl[buf][d * 64] +
                                     ((k2 * 64 + lg * 16) ^ swz));
        o[0][nf] = MFMA(pa[0], bv, o[0][nf]);
        o[1][nf] = MFMA(pa[1], bv, o[1][nf]);
      }
    }
    buf ^= 1;
  }

  // ---- epilogue: lsv already in o[] layout; divide & store ----
  u16* Op = attn_o + (size_t)b * 2048 * 2048 + h * 64;
#pragma unroll
  for (int qh = 0; qh < 2; ++qh) {
#pragma unroll
    for (int j = 0; j < 4; ++j) {
      const float inv = __builtin_amdgcn_rcpf(lsv[qh][j]);
      const int row = q0 + qh * 16 + lg * 4 + j;
#pragma unroll
      for (int nf = 0; nf < 4; ++nf)
        Op[(size_t)row * 2048 + nf * 16 + lr] = f2bf(o[qh][nf][j] * inv);
    }
  }
}

// ---------------- launch ----------------
extern "C" void kernel_launch(void* const* d_in, const int* in_sizes, int n_in,
                              void* d_out, int out_size, void* d_ws, size_t ws_size,
                              hipStream_t stream) {
  const float* x = (const float*)d_in[0];
  const float* wq = (const float*)d_in[1];
  const float* wk = (const float*)d_in[2];
  const float* wv = (const float*)d_in[3];
  const float* wo = (const float*)d_in[4];
  float* out = (float*)d_out;

  char* p = (char*)d_ws;
  auto alloc = [&](size_t bytes) {
    char* r = p;
    p += (bytes + 255) & ~(size_t)255;
    return r;
  };
  u16* x_bf    = (u16*)alloc((size_t)8388608 * 2);
  u16* wqkv    = (u16*)alloc((size_t)3072 * 2048 * 2);
  u16* wo_bf   = (u16*)alloc((size_t)2048 * 2048 * 2);
  u16* q_r     = (u16*)alloc((size_t)8388608 * 2);
  u16* k_r     = (u16*)alloc((size_t)2097152 * 2);
  u16* v_t     = (u16*)alloc((size_t)2097152 * 2);
  u16* attn_o  = (u16*)alloc((size_t)8388608 * 2);
  float2* cs   = (float2*)alloc((size_t)65536 * 8);

  cvt_all<<<18432, 256, 0, stream>>>(x, wq, wk, wv, wo, x_bf, wqkv, wo_bf);
  rope_cs<<<256, 256, 0, stream>>>(cs);

  // QKV projection, 256^2 phase-split: (4096x2048) x (3072x2048)^T
  gemm_qkv<<<192, 512, 0, stream>>>(x_bf, wqkv, cs, q_r, k_r, v_t);

  attn4<<<1024, 256, 0, stream>>>(q_r, k_r, v_t, attn_o);

  // output projection, 256x128 phase-split: (4096x2048) x (2048x2048)^T
  gemm_o<<<256, 512, 0, stream>>>(attn_o, wo_bf, out);
}

// Round 8
// 301.762 us; speedup vs baseline: 1.1436x; 1.0545x over previous
//
#include <hip/hip_runtime.h>

using u16 = unsigned short;
using u32 = unsigned int;
typedef __attribute__((ext_vector_type(8))) short bf16x8;
typedef __attribute__((ext_vector_type(4))) float f32x4;
typedef __attribute__((ext_vector_type(4))) float float4v;
typedef __attribute__((ext_vector_type(4))) unsigned short us4;
typedef __attribute__((ext_vector_type(2))) unsigned int u32x2;

__device__ __forceinline__ u16 f2bf(float f) {
  union { float f; unsigned u; } v; v.f = f;
  unsigned r = v.u + 0x7fffu + ((v.u >> 16) & 1u);
  return (u16)(r >> 16);
}

__device__ __forceinline__ u32 cvtpk(float a, float b) {
  u32 r;
  asm("v_cvt_pk_bf16_f32 %0, %1, %2" : "=v"(r) : "v"(a), "v"(b));
  return r;
}

__device__ __forceinline__ void glds16(const void* g, void* l) {
  __builtin_amdgcn_global_load_lds(
      (const __attribute__((address_space(1))) void*)g,
      (__attribute__((address_space(3))) void*)l, 16, 0, 0);
}

__device__ __forceinline__ void lgkm0() {
  asm volatile("s_waitcnt lgkmcnt(0)" ::: "memory");
}

#define SCHED0() __builtin_amdgcn_sched_barrier(0)

#define MFMA(a, b, c) __builtin_amdgcn_mfma_f32_16x16x32_bf16((a), (b), (c), 0, 0, 0)

// scale folded into Q at projection time: 1/sqrt(64) * log2(e)
#define QSCALE 0.1803368801111601f

// ---------------- fused fp32 -> bf16 cast for all 5 inputs ----------------
__global__ __launch_bounds__(256) void cvt_all(
    const float* __restrict__ x, const float* __restrict__ wq,
    const float* __restrict__ wk, const float* __restrict__ wv,
    const float* __restrict__ wo, u16* __restrict__ x_bf,
    u16* __restrict__ wqkv, u16* __restrict__ wo_bf) {
  int i = blockIdx.x * 256 + threadIdx.x;   // 4718592 total
  const float4v* src;
  us4* dst;
  if (i < 2097152) {
    src = (const float4v*)x + i; dst = (us4*)x_bf + i;
  } else if (i < 3145728) {
    int j = i - 2097152; src = (const float4v*)wq + j; dst = (us4*)wqkv + j;
  } else if (i < 3407872) {
    int j = i - 3145728; src = (const float4v*)wk + j; dst = (us4*)wqkv + 1048576 + j;
  } else if (i < 3670016) {
    int j = i - 3407872; src = (const float4v*)wv + j; dst = (us4*)wqkv + 1310720 + j;
  } else {
    int j = i - 3670016; src = (const float4v*)wo + j; dst = (us4*)wo_bf + j;
  }
  float4v v = *src;
  us4 o;
  o[0] = f2bf(v[0]); o[1] = f2bf(v[1]); o[2] = f2bf(v[2]); o[3] = f2bf(v[3]);
  *dst = o;
}

// ---------------- RoPE cos/sin table: (L=2048, 32) float2 ----------------
__global__ __launch_bounds__(256) void rope_cs(float2* __restrict__ cs) {
  int i = blockIdx.x * 256 + threadIdx.x;
  if (i >= 2048 * 32) return;
  int t = i >> 5, fi = i & 31;
  float inv = powf(10000.f, -(float)fi / 32.f);
  float ang = (float)t * inv;
  cs[i] = make_float2(cosf(ang), sinf(ang));
}

// ---------------- QKV GEMM: 256x256, BK=64, 8 waves -----------------------
// Design C: 2 barriers/tile, counted vmcnt(8), free wave drift in compute.
__global__ __launch_bounds__(512, 2) void gemm_qkv(const u16* __restrict__ Ag,
                                                   const u16* __restrict__ Bg,
                                                   const float2* __restrict__ cs,
                                                   u16* __restrict__ q_r,
                                                   u16* __restrict__ k_r,
                                                   u16* __restrict__ v_t) {
  __shared__ u16 Al[2][256 * 64];   // 64KB
  __shared__ u16 Bl[2][256 * 64];   // 64KB

  const int nwg = gridDim.x;        // 192
  const int cpx = nwg >> 3;
  const int flat = blockIdx.x;
  const int swb = (flat & 7) * cpx + (flat >> 3);
  const int bx = swb & 15, by = swb >> 4;
  const int bmRow = bx * 256, bnRow = by * 256;

  const int tid = threadIdx.x;
  const int w = tid >> 6, l = tid & 63;
  const int wm = w >> 2, wn = w & 3;      // rows wm*128, cols wn*64
  const int lr = l & 15, lg = l >> 4;
  const int rb7 = lr & 7;

  // staging: each wave owns 32 rows of A-tile and 32 rows of B-tile
  const int srow = l >> 3;
  const int sch = (l & 7) ^ srow;         // pre-swizzled source chunk (T2)
  const int reg0 = w * 32;
  const u16* a_src = Ag + (size_t)(bmRow + reg0 + srow) * 2048 + sch * 8;
  const u16* b_src = Bg + (size_t)(bnRow + reg0 + srow) * 2048 + sch * 8;

  auto stageTile = [&](int kt, int bufi) {
    const int kc = kt * 64;
#pragma unroll
    for (int i = 0; i < 4; ++i)
      glds16(a_src + (size_t)i * 8 * 2048 + kc, &Al[bufi][(reg0 + i * 8) * 64]);
#pragma unroll
    for (int i = 0; i < 4; ++i)
      glds16(b_src + (size_t)i * 8 * 2048 + kc, &Bl[bufi][(reg0 + i * 8) * 64]);
  };
  // swizzled ds_read: row in [0,256), chunk g in [0,8)
  auto rd = [&](const u16* base, int row, int g) -> bf16x8 {
    return *(const bf16x8*)((const char*)base + row * 128 + (((g) ^ rb7) << 4));
  };

  f32x4 acc[8][4];
#pragma unroll
  for (int m = 0; m < 8; ++m)
#pragma unroll
    for (int n = 0; n < 4; ++n) acc[m][n] = f32x4{0.f, 0.f, 0.f, 0.f};

  bf16x8 af[4][2], bfr[4][2];
  const int NT = 32;

  stageTile(0, 0);
  for (int t = 0; t < NT; ++t) {
    const int cur = t & 1;
    const u16* Ab = &Al[cur][0];
    const u16* Bb = &Bl[cur][0];

    __builtin_amdgcn_s_barrier();         // bar1: all waves done reading buf[cur^1]
    SCHED0();
    if (t + 1 < NT) {
      stageTile(t + 1, cur ^ 1);          // 8 glds; stay in flight across bar2
      asm volatile("s_waitcnt vmcnt(8)" ::: "memory");   // tile t landed
    } else {
      asm volatile("s_waitcnt vmcnt(0)" ::: "memory");
    }
    __builtin_amdgcn_s_barrier();         // bar2: tile t visible to all waves
    SCHED0();

    // ---- compute tile t: no internal barriers; waves drift freely ----
#pragma unroll
    for (int m = 0; m < 4; ++m)
#pragma unroll
      for (int kk = 0; kk < 2; ++kk)
        af[m][kk] = rd(Ab, wm * 128 + m * 16 + lr, kk * 4 + lg);
#pragma unroll
    for (int n = 0; n < 4; ++n)
#pragma unroll
      for (int kk = 0; kk < 2; ++kk)
        bfr[n][kk] = rd(Bb, wn * 64 + n * 16 + lr, kk * 4 + lg);
    __builtin_amdgcn_s_setprio(1);
#pragma unroll
    for (int m = 0; m < 4; ++m)
#pragma unroll
      for (int n = 0; n < 4; ++n)
#pragma unroll
        for (int kk = 0; kk < 2; ++kk)
          acc[m][n] = MFMA(af[m][kk], bfr[n][kk], acc[m][n]);
    __builtin_amdgcn_s_setprio(0);
#pragma unroll
    for (int m = 0; m < 4; ++m)
#pragma unroll
      for (int kk = 0; kk < 2; ++kk)
        af[m][kk] = rd(Ab, wm * 128 + 64 + m * 16 + lr, kk * 4 + lg);
    __builtin_amdgcn_s_setprio(1);
#pragma unroll
    for (int m = 0; m < 4; ++m)
#pragma unroll
      for (int n = 0; n < 4; ++n)
#pragma unroll
        for (int kk = 0; kk < 2; ++kk)
          acc[4 + m][n] = MFMA(af[m][kk], bfr[n][kk], acc[4 + m][n]);
    __builtin_amdgcn_s_setprio(0);
  }

  // ---- epilogue: fused RoPE / layout (wave col span = 64 = one head) ----
  const int cbcol = bnRow + wn * 64;
  const int rowbase = bmRow + wm * 128;

  if (cbcol < 2560) {
    const bool isQ = (cbcol < 2048);
    const int h = (isQ ? cbcol : cbcol - 2048) >> 6;
    u16* dst = isQ ? q_r : k_r;
    const int nh = isQ ? 32 : 8;
#pragma unroll
    for (int m = 0; m < 8; ++m) {
#pragma unroll
      for (int j = 0; j < 4; ++j) {
        const int row = rowbase + m * 16 + lg * 4 + j;
        const int b = row >> 11, ll = row & 2047;
        const float2 c0 = cs[ll * 32 + lr];
        const float2 c1 = cs[ll * 32 + 16 + lr];
        u16* op = dst + (((size_t)b * nh + h) * 2048 + ll) * 64;
#pragma unroll
        for (int n = 0; n < 4; ++n) {
          const float val = acc[m][n][j];
          const float oth = acc[m][n ^ 2][j];
          const float cx = (n & 1) ? c1.x : c0.x;
          const float sy = (n & 1) ? c1.y : c0.y;
          float r = (n < 2) ? (val * cx - oth * sy) : (val * cx + oth * sy);
          if (isQ) r *= QSCALE;
          op[n * 16 + lr] = f2bf(r);
        }
      }
    }
  } else {
    const int h = (cbcol - 2560) >> 6;
#pragma unroll
    for (int m = 0; m < 8; ++m) {
      const int row0 = rowbase + m * 16 + lg * 4;
      const int b = row0 >> 11, l0 = row0 & 2047;
#pragma unroll
      for (int n = 0; n < 4; ++n) {
        const int d = n * 16 + lr;
        us4 pk;
#pragma unroll
        for (int j = 0; j < 4; ++j) pk[j] = f2bf(acc[m][n][j]);
        *(us4*)&v_t[(((size_t)b * 8 + h) * 64 + d) * 2048 + l0] = pk;
      }
    }
  }
}

// ---------------- out-proj GEMM: 256x128 tile, design C --------------------
// C = A(4096x2048) * B(2048x2048)^T, fp32 out. Grid 256 (full CU fill).
__global__ __launch_bounds__(512, 2) void gemm_o(const u16* __restrict__ Ag,
                                                 const u16* __restrict__ Bg,
                                                 float* __restrict__ C) {
  __shared__ u16 Al[2][256 * 64];   // 64KB
  __shared__ u16 Bl[2][128 * 64];   // 32KB

  const int nwg = gridDim.x;        // 256
  const int cpx = nwg >> 3;
  const int flat = blockIdx.x;
  const int swb = (flat & 7) * cpx + (flat >> 3);
  const int bx = swb & 15, by = swb >> 4;
  const int bmRow = bx * 256, bnRow = by * 128;

  const int tid = threadIdx.x;
  const int w = tid >> 6, l = tid & 63;
  const int wm = w >> 1, wn = w & 1;      // rows wm*64, cols wn*64
  const int lr = l & 15, lg = l >> 4;
  const int rb7 = lr & 7;

  const int srow = l >> 3;
  const int sch = (l & 7) ^ srow;
  const int areg = w * 32;                // A: 32 rows/wave (4 glds)
  const int breg = w * 16;                // B: 16 rows/wave (2 glds)
  const u16* a_src = Ag + (size_t)(bmRow + areg + srow) * 2048 + sch * 8;
  const u16* b_src = Bg + (size_t)(bnRow + breg + srow) * 2048 + sch * 8;

  auto stageTile = [&](int kt, int bufi) {
    const int kc = kt * 64;
#pragma unroll
    for (int i = 0; i < 4; ++i)
      glds16(a_src + (size_t)i * 8 * 2048 + kc, &Al[bufi][(areg + i * 8) * 64]);
#pragma unroll
    for (int i = 0; i < 2; ++i)
      glds16(b_src + (size_t)i * 8 * 2048 + kc, &Bl[bufi][(breg + i * 8) * 64]);
  };
  auto rd = [&](const u16* base, int row, int g) -> bf16x8 {
    return *(const bf16x8*)((const char*)base + row * 128 + (((g) ^ rb7) << 4));
  };

  f32x4 acc[4][4];
#pragma unroll
  for (int m = 0; m < 4; ++m)
#pragma unroll
    for (int n = 0; n < 4; ++n) acc[m][n] = f32x4{0.f, 0.f, 0.f, 0.f};

  bf16x8 af[4][2], bfr[4][2];
  const int NT = 32;

  stageTile(0, 0);
  for (int t = 0; t < NT; ++t) {
    const int cur = t & 1;
    const u16* Ab = &Al[cur][0];
    const u16* Bb = &Bl[cur][0];

    __builtin_amdgcn_s_barrier();
    SCHED0();
    if (t + 1 < NT) {
      stageTile(t + 1, cur ^ 1);
      asm volatile("s_waitcnt vmcnt(6)" ::: "memory");
    } else {
      asm volatile("s_waitcnt vmcnt(0)" ::: "memory");
    }
    __builtin_amdgcn_s_barrier();
    SCHED0();

#pragma unroll
    for (int m = 0; m < 4; ++m)
#pragma unroll
      for (int kk = 0; kk < 2; ++kk)
        af[m][kk] = rd(Ab, wm * 64 + m * 16 + lr, kk * 4 + lg);
#pragma unroll
    for (int n = 0; n < 4; ++n)
#pragma unroll
      for (int kk = 0; kk < 2; ++kk)
        bfr[n][kk] = rd(Bb, wn * 64 + n * 16 + lr, kk * 4 + lg);
    __builtin_amdgcn_s_setprio(1);
#pragma unroll
    for (int m = 0; m < 4; ++m)
#pragma unroll
      for (int n = 0; n < 4; ++n)
#pragma unroll
        for (int kk = 0; kk < 2; ++kk)
          acc[m][n] = MFMA(af[m][kk], bfr[n][kk], acc[m][n]);
    __builtin_amdgcn_s_setprio(0);
  }

  float* Cp = C + (size_t)(bmRow + wm * 64) * 2048 + bnRow + wn * 64;
#pragma unroll
  for (int m = 0; m < 4; ++m)
#pragma unroll
    for (int n = 0; n < 4; ++n)
#pragma unroll
      for (int j = 0; j < 4; ++j)
        Cp[(size_t)(m * 16 + lg * 4 + j) * 2048 + n * 16 + lr] = acc[m][n][j];
}

// ---------------- causal GQA flash attention v4 (unchanged) ----------------
__global__ __launch_bounds__(256) void attn4(const u16* __restrict__ q_r,
                                             const u16* __restrict__ k_r,
                                             const u16* __restrict__ v_t,
                                             u16* __restrict__ attn_o) {
  __shared__ u16 Kl[2][64 * 64];    // [buf][kv][d] swizzled
  __shared__ u16 Vl[2][64 * 64];    // [buf][d][kv] swizzled
  __shared__ u16 Pl[4][32 * 64];    // per-wave [q][kv] swizzled

  const int bid = blockIdx.x;             // 1024 blocks
  const int q0 = (63 - (bid >> 4)) * 32;  // longest blocks first
  const int bk = bid & 15;
  const int b = bk >> 3, kvh = bk & 7;

  const int tid = threadIdx.x;
  const int w = tid >> 6;                 // wave = q-head within kv group
  const int l = tid & 63;
  const int h = kvh * 4 + w;
  const int lr = l & 15, lg = l >> 4;

  const u16* Qp = q_r + (((size_t)(b * 32 + h)) * 2048 + q0) * 64;
  const u16* Kp = k_r + ((size_t)(b * 8 + kvh)) * 2048 * 64;
  const u16* Vp = v_t + ((size_t)(b * 8 + kvh)) * 64 * 2048;

  bf16x8 qf[2][2];
#pragma unroll
  for (int qh = 0; qh < 2; ++qh)
#pragma unroll
    for (int kh = 0; kh < 2; ++kh)
      qf[qh][kh] = *(const bf16x8*)&Qp[(qh * 16 + lr) * 64 + kh * 32 + lg * 8];

  bf16x8 ones;
#pragma unroll
  for (int i = 0; i < 8; ++i) ones[i] = (short)0x3F80;   // bf16 1.0

  f32x4 o[2][4];
#pragma unroll
  for (int qh = 0; qh < 2; ++qh)
#pragma unroll
    for (int nf = 0; nf < 4; ++nf) o[qh][nf] = f32x4{0.f, 0.f, 0.f, 0.f};
  f32x4 lsv[2] = {f32x4{0.f, 0.f, 0.f, 0.f}, f32x4{0.f, 0.f, 0.f, 0.f}};

  const int sr = l >> 3;
  const int sc = (l & 7) ^ sr;            // pre-swizzled source chunk
  const int nt = (q0 + 95) >> 6;
  const int nfull = q0 >> 6;

  auto stage = [&](int bufi, int t) {
#pragma unroll
    for (int p = 0; p < 2; ++p) {
      const int r = p * 32 + w * 8 + sr;
      glds16(Kp + (size_t)(t * 64 + r) * 64 + sc * 8, &Kl[bufi][(p * 32 + w * 8) * 64]);
      glds16(Vp + (size_t)r * 2048 + t * 64 + sc * 8, &Vl[bufi][(p * 32 + w * 8) * 64]);
    }
  };

  stage(0, 0);
  int buf = 0;
  for (int t = 0; t < nt; ++t) {
    __syncthreads();
    if (t + 1 < nt) stage(buf ^ 1, t + 1);
    const int kv0 = t * 64;

    // ---- QK^T (swapped: A=K rows, B=Q rows); exp2-domain scores ----
    f32x4 s[2][4];
#pragma unroll
    for (int qh = 0; qh < 2; ++qh)
#pragma unroll
      for (int kv4 = 0; kv4 < 4; ++kv4) s[qh][kv4] = f32x4{0.f, 0.f, 0.f, 0.f};
    const int swz = (lr & 7) << 4;
#pragma unroll
    for (int kv4 = 0; kv4 < 4; ++kv4) {
      const int kvr = kv4 * 16 + lr;
#pragma unroll
      for (int kh = 0; kh < 2; ++kh) {
        bf16x8 kf = *(const bf16x8*)((const char*)&Kl[buf][kvr * 64] +
                                     ((kh * 64 + lg * 16) ^ swz));
        s[0][kv4] = MFMA(kf, qf[0][kh], s[0][kv4]);
        s[1][kv4] = MFMA(kf, qf[1][kh], s[1][kv4]);
      }
    }

    const bool diag = (t >= nfull);       // one masked tile per block
#pragma unroll
    for (int qh = 0; qh < 2; ++qh) {
      const int qrow = q0 + qh * 16 + lr;
      if (diag) {
#pragma unroll
        for (int kv4 = 0; kv4 < 4; ++kv4)
#pragma unroll
          for (int j = 0; j < 4; ++j)
            if ((kv0 + kv4 * 16 + lg * 4 + j) > qrow) s[qh][kv4][j] = -1e30f;
      }
#pragma unroll
      for (int kv4 = 0; kv4 < 4; ++kv4) {
        u32x2 pk;
        pk[0] = cvtpk(exp2f(s[qh][kv4][0]), exp2f(s[qh][kv4][1]));
        pk[1] = cvtpk(exp2f(s[qh][kv4][2]), exp2f(s[qh][kv4][3]));
        *(u32x2*)((char*)&Pl[w][(qh * 16 + lr) * 64] +
                  ((kv4 * 32 + lg * 8) ^ swz)) = pk;
      }
    }

    // ---- PV: A=P, B=V^T rows; lsum via ones-fragment MFMA ----
    lgkm0();
#pragma unroll
    for (int k2 = 0; k2 < 2; ++k2) {
      bf16x8 pa[2];
#pragma unroll
      for (int qh = 0; qh < 2; ++qh)
        pa[qh] = *(const bf16x8*)((const char*)&Pl[w][(qh * 16 + lr) * 64] +
                                  ((k2 * 64 + lg * 16) ^ swz));
      lsv[0] = MFMA(pa[0], ones, lsv[0]);
      lsv[1] = MFMA(pa[1], ones, lsv[1]);
#pragma unroll
      for (int nf = 0; nf < 4; ++nf) {
        const int d = nf * 16 + lr;
        bf16x8 bv = *(const bf16x8*)((const char*)&Vl[buf][d * 64] +
                                     ((k2 * 64 + lg * 16) ^ swz));
        o[0][nf] = MFMA(pa[0], bv, o[0][nf]);
        o[1][nf] = MFMA(pa[1], bv, o[1][nf]);
      }
    }
    buf ^= 1;
  }

  // ---- epilogue: lsv already in o[] layout; divide & store ----
  u16* Op = attn_o + (size_t)b * 2048 * 2048 + h * 64;
#pragma unroll
  for (int qh = 0; qh < 2; ++qh) {
#pragma unroll
    for (int j = 0; j < 4; ++j) {
      const float inv = __builtin_amdgcn_rcpf(lsv[qh][j]);
      const int row = q0 + qh * 16 + lg * 4 + j;
#pragma unroll
      for (int nf = 0; nf < 4; ++nf)
        Op[(size_t)row * 2048 + nf * 16 + lr] = f2bf(o[qh][nf][j] * inv);
    }
  }
}

// ---------------- launch ----------------
extern "C" void kernel_launch(void* const* d_in, const int* in_sizes, int n_in,
                              void* d_out, int out_size, void* d_ws, size_t ws_size,
                              hipStream_t stream) {
  const float* x = (const float*)d_in[0];
  const float* wq = (const float*)d_in[1];
  const float* wk = (const float*)d_in[2];
  const float* wv = (const float*)d_in[3];
  const float* wo = (const float*)d_in[4];
  float* out = (float*)d_out;

  char* p = (char*)d_ws;
  auto alloc = [&](size_t bytes) {
    char* r = p;
    p += (bytes + 255) & ~(size_t)255;
    return r;
  };
  u16* x_bf    = (u16*)alloc((size_t)8388608 * 2);
  u16* wqkv    = (u16*)alloc((size_t)3072 * 2048 * 2);
  u16* wo_bf   = (u16*)alloc((size_t)2048 * 2048 * 2);
  u16* q_r     = (u16*)alloc((size_t)8388608 * 2);
  u16* k_r     = (u16*)alloc((size_t)2097152 * 2);
  u16* v_t     = (u16*)alloc((size_t)2097152 * 2);
  u16* attn_o  = (u16*)alloc((size_t)8388608 * 2);
  float2* cs   = (float2*)alloc((size_t)65536 * 8);

  cvt_all<<<18432, 256, 0, stream>>>(x, wq, wk, wv, wo, x_bf, wqkv, wo_bf);
  rope_cs<<<256, 256, 0, stream>>>(cs);

  // QKV projection, 256^2 design-C: (4096x2048) x (3072x2048)^T
  gemm_qkv<<<192, 512, 0, stream>>>(x_bf, wqkv, cs, q_r, k_r, v_t);

  attn4<<<1024, 256, 0, stream>>>(q_r, k_r, v_t, attn_o);

  // output projection, 256x128 design-C: (4096x2048) x (2048x2048)^T
  gemm_o<<<256, 512, 0, stream>>>(attn_o, wo_bf, out);
}